// Round 1
// baseline (252.126 us; speedup 1.0000x reference)
//
#include <hip/hip_runtime.h>
#include <math.h>

#define S 8192
#define E 64
#define CAP 256
static const long long NOUT = (long long)S * E * CAP;  // 134,217,728 elems per output

// ---------------------------------------------------------------------------
// Kernel A: per-row fp32 softmax + top-1/top-2 selection.
// One wave (64 lanes) per row; lane == expert index. 4 rows per block.
// ---------------------------------------------------------------------------
__global__ void softmax_top2(const float* __restrict__ in,
                             int* __restrict__ idx1, int* __restrict__ idx2,
                             float* __restrict__ w1, float* __restrict__ w2) {
    const int lane = threadIdx.x;          // 0..63, == expert id
    const int row  = blockIdx.x * 4 + threadIdx.y;

    float x = in[row * E + lane];

    // wave max
    float mx = x;
    #pragma unroll
    for (int o = 32; o > 0; o >>= 1) mx = fmaxf(mx, __shfl_xor(mx, o));

    float p = __expf(x - mx);
    float sum = p;
    #pragma unroll
    for (int o = 32; o > 0; o >>= 1) sum += __shfl_xor(sum, o);
    float prob = p / sum;

    // argmax on x (same order as prob), first-index tie-break like jnp.argmax
    float v = x; int idx = lane;
    #pragma unroll
    for (int o = 32; o > 0; o >>= 1) {
        float ov = __shfl_xor(v, o);
        int   oi = __shfl_xor(idx, o);
        if (ov > v || (ov == v && oi < idx)) { v = ov; idx = oi; }
    }
    const int i1 = idx;

    // top-2: mask out top-1, argmax again
    float x2 = (lane == i1) ? -INFINITY : x;
    v = x2; idx = lane;
    #pragma unroll
    for (int o = 32; o > 0; o >>= 1) {
        float ov = __shfl_xor(v, o);
        int   oi = __shfl_xor(idx, o);
        if (ov > v || (ov == v && oi < idx)) { v = ov; idx = oi; }
    }
    const int i2 = idx;

    const float pw1 = __shfl(prob, i1);
    const float pw2 = __shfl(prob, i2);

    if (lane == 0) {
        idx1[row] = i1;
        idx2[row] = i2;
        w1[row]   = pw1;
        w2[row]   = pw2;
    }
}

// ---------------------------------------------------------------------------
// Kernel B: exclusive rank per expert via ballot+popcount prefix.
// Block b owns expert b (64 blocks, 1 wave each). Pass 1 computes rank1 and,
// as a side effect, count1[e] (loop-carried base). Pass 2 computes rank2
// offset by count1[e] — no inter-block dependency since the offset is
// per-expert-column.
// ---------------------------------------------------------------------------
__global__ void rank_kernel(const int* __restrict__ idx1,
                            const int* __restrict__ idx2,
                            int* __restrict__ rank1, int* __restrict__ rank2) {
    const int e    = blockIdx.x;
    const int lane = threadIdx.x;
    const unsigned long long below = (lane == 0) ? 0ULL : ((1ULL << lane) - 1ULL);

    int base = 0;
    for (int t0 = 0; t0 < S; t0 += 64) {
        const int t = t0 + lane;
        const int i = idx1[t];
        const unsigned long long m = __ballot(i == e);
        if (i == e) rank1[t] = base + __popcll(m & below);
        base += __popcll(m);
    }
    // base == count1[e] == sum(mask1[:, e])
    int base2 = base;
    for (int t0 = 0; t0 < S; t0 += 64) {
        const int t = t0 + lane;
        const int i = idx2[t];
        const unsigned long long m = __ballot(i == e);
        if (i == e) rank2[t] = base2 + __popcll(m & below);
        base2 += __popcll(m);
    }
}

// ---------------------------------------------------------------------------
// Kernel C: sparse scatter into the (pre-zeroed) [S,E,CAP] cb_weight and
// sec_mask outputs. One thread per token, <=2 entries each.
// ---------------------------------------------------------------------------
__global__ void scatter_kernel(const int* __restrict__ idx1,
                               const int* __restrict__ idx2,
                               const float* __restrict__ w1,
                               const float* __restrict__ w2,
                               const int* __restrict__ rank1,
                               const int* __restrict__ rank2,
                               float* __restrict__ out) {
    const int t = blockIdx.x * blockDim.x + threadIdx.x;
    if (t >= S) return;

    float* __restrict__ cb   = out;
    float* __restrict__ mask = out + NOUT;

    const int r1 = rank1[t];
    if (r1 < CAP) {
        const long long off = (long long)t * (E * CAP) + (long long)idx1[t] * CAP + r1;
        const float w = w1[t];
        cb[off]   = w;
        mask[off] = (w != 0.0f) ? 1.0f : 0.0f;
    }
    const int r2 = rank2[t];
    if (r2 < CAP) {
        const long long off = (long long)t * (E * CAP) + (long long)idx2[t] * CAP + r2;
        const float w = w2[t];
        cb[off]   = w;
        mask[off] = (w != 0.0f) ? 1.0f : 0.0f;
    }
}

extern "C" void kernel_launch(void* const* d_in, const int* in_sizes, int n_in,
                              void* d_out, int out_size, void* d_ws, size_t ws_size,
                              hipStream_t stream) {
    const float* in = (const float*)d_in[0];
    float* out = (float*)d_out;

    // workspace layout (all int/float, 8192 each): idx1, idx2, rank1, rank2, w1, w2
    int*   idx1  = (int*)d_ws;
    int*   idx2  = idx1 + S;
    int*   rank1 = idx2 + S;
    int*   rank2 = rank1 + S;
    float* w1    = (float*)(rank2 + S);
    float* w2    = w1 + S;

    // Zero the full 1 GiB output (poisoned to 0xAA by harness; must be
    // rewritten every call). Memset nodes are graph-capturable.
    hipMemsetAsync(d_out, 0, (size_t)out_size * sizeof(float), stream);

    softmax_top2<<<S / 4, dim3(64, 4), 0, stream>>>(in, idx1, idx2, w1, w2);
    rank_kernel<<<E, 64, 0, stream>>>(idx1, idx2, rank1, rank2);
    scatter_kernel<<<(S + 255) / 256, 256, 0, stream>>>(idx1, idx2, w1, w2,
                                                        rank1, rank2, out);
}